// Round 7
// baseline (196.344 us; speedup 1.0000x reference)
//
#include <hip/hip_runtime.h>
#include <hip/hip_bf16.h>
#include <stdint.h>

#define IN_F 4096
#define OUT_F 11008
#define NUM_CH 128
#define NUM_NORM 3968
#define BATCH 64
#define KB_N 124          // 32-k blocks in normal region (3968/32)
#define KSPLIT 8
#define KCHUNK 512        // k per qgemm block
#define NSUB 16           // 32-k substeps per block

typedef short short8 __attribute__((ext_vector_type(8)));
typedef float float4v __attribute__((ext_vector_type(4)));
typedef unsigned uint4v __attribute__((ext_vector_type(4)));

__device__ __forceinline__ unsigned short f2bf(float f) {
    union { float f; unsigned u; } v; v.f = f;
    unsigned u = v.u;
    return (unsigned short)((u + 0x7FFFu + ((u >> 16) & 1u)) >> 16);
}

__device__ __forceinline__ unsigned pk_bf16(float lo, float hi) {
    __hip_bfloat162 h = __float22bfloat162_rn(make_float2(lo, hi));  // v_cvt_pk_bf16_f32
    union { __hip_bfloat162 h; unsigned u; } c; c.h = h; return c.u;
}

// out[m][n] = bias[n]  (pre-init so qgemm can atomicAdd partials)
__global__ __launch_bounds__(256) void init_out(
        const float* __restrict__ bias, float* __restrict__ out) {
    const int i = blockIdx.x * 256 + threadIdx.x;
    const int c = i % (OUT_F / 4);
    const float4v b4 = *reinterpret_cast<const float4v*>(bias + c * 4);
    reinterpret_cast<float4v*>(out)[i] = b4;
}

// Gather-permute x into bf16 xp[64][4096]:
//   pos j in [0,3968): x[:, normal_idx[j]]   pos 3968+c: x[:, cherry_indices[c]]
__global__ __launch_bounds__(256) void permute_x(
        const float* __restrict__ x, const int* __restrict__ cidx,
        unsigned short* __restrict__ xp) {
    int i = blockIdx.x * blockDim.x + threadIdx.x;
    int b = blockIdx.y;
    int lo = 0, hi = NUM_CH;
    while (lo < hi) { int mid = (lo + hi) >> 1; if (cidx[mid] < i) lo = mid + 1; else hi = mid; }
    bool isch = (lo < NUM_CH) && (cidx[lo] == i);
    int pos = isch ? (NUM_NORM + lo) : (i - lo);
    xp[b * IN_F + pos] = f2bf(x[b * IN_F + i]);
}

// Repack qweight (int32-widened bytes, row-major [1984][11008]) into MFMA
// B-fragment-major bytes: pk[kb][n][16], where byte r of the 16 is packed row
// kb*16+r of column n. Lane (n,lq)'s B-frag for k-block kb = dword lq of
// pk[kb][n] (bytes r=lq*4..lq*4+3 hold k = lq*8..lq*8+7 as nibble pairs).
__global__ __launch_bounds__(256) void repack_n(
        const int* __restrict__ qw, unsigned char* __restrict__ pk) {
    const int kb = blockIdx.y;
    const int n  = blockIdx.x * 256 + threadIdx.x;
    const int* src = qw + (size_t)kb * 16 * OUT_F + n;   // reads: 256B-coalesced per row
    unsigned dw[4];
    #pragma unroll
    for (int a = 0; a < 4; ++a) {
        const unsigned b0 = (unsigned)src[(size_t)(4 * a + 0) * OUT_F] & 0xFFu;
        const unsigned b1 = (unsigned)src[(size_t)(4 * a + 1) * OUT_F] & 0xFFu;
        const unsigned b2 = (unsigned)src[(size_t)(4 * a + 2) * OUT_F] & 0xFFu;
        const unsigned b3 = (unsigned)src[(size_t)(4 * a + 3) * OUT_F] & 0xFFu;
        dw[a] = b0 | (b1 << 8) | (b2 << 16) | (b3 << 24);
    }
    *reinterpret_cast<uint4v*>(pk + ((size_t)kb * OUT_F + n) * 16) =
        (uint4v){dw[0], dw[1], dw[2], dw[3]};   // 16B/thread, wave = 4KB contiguous
}

// Repack cherry fp32 [128][11008] into bf16 B-fragments:
// pkc[kbc][n][32 shorts]; frag lq = shorts lq*8..+7 = k kbc*32+lq*8..+7.
__global__ __launch_bounds__(256) void repack_ch(
        const float* __restrict__ cw, unsigned short* __restrict__ pkc) {
    const int kbc = blockIdx.y;                    // 0..3
    const int n   = blockIdx.x * 256 + threadIdx.x;
    const float* src = cw + (size_t)kbc * 32 * OUT_F + n;
    unsigned u[16];
    #pragma unroll
    for (int j = 0; j < 16; ++j)
        u[j] = pk_bf16(src[(size_t)(2 * j) * OUT_F], src[(size_t)(2 * j + 1) * OUT_F]);
    uint4v* dst = reinterpret_cast<uint4v*>(pkc + ((size_t)kbc * OUT_F + n) * 32);
    #pragma unroll
    for (int q = 0; q < 4; ++q)
        dst[q] = (uint4v){u[4 * q], u[4 * q + 1], u[4 * q + 2], u[4 * q + 3]};
}

// LDS-free, barrier-free fused dequant GEMM. Wave owns a 32-n stripe; all 16
// substeps' B-words are prefetched up front (1 coalesced dword/lane/32k from
// pk); dequant to B-frags in regs; A from xp (L1-shared across the block's 4
// waves). 8 MFMAs per 32-k substep (4 m-tiles x 2 n-frags). KSPLIT=8 partials
// atomically accumulated into bias-initialized out.
__global__ __launch_bounds__(256) void qgemm(
        const unsigned short* __restrict__ xp, const unsigned* __restrict__ pk,
        const unsigned short* __restrict__ pkc, const float* __restrict__ scales,
        float* __restrict__ out) {
    const int tid  = threadIdx.x;
    const int wave = tid >> 6;
    const int lane = tid & 63;
    const int ln   = lane & 15;
    const int lq   = lane >> 4;
    const int n0w  = (blockIdx.x * 4 + wave) * 32;
    const int ky   = blockIdx.y;
    const int kbase = ky * KCHUNK;
    const int kb0   = ky * 16;
    const bool chblk = (ky == KSPLIT - 1);
    const int nsubn  = chblk ? 12 : 16;    // normal substeps in this chunk

    const int nc0 = n0w + ln;
    const int nc1 = n0w + 16 + ln;

    // ---- prefetch ALL B data for the chunk (stays in flight; no barrier ever) ----
    unsigned bq[16][2];
    #pragma unroll
    for (int sub = 0; sub < 16; ++sub) {
        if (sub < nsubn) {
            bq[sub][0] = pk[((size_t)(kb0 + sub) * OUT_F + nc0) * 4 + lq];
            bq[sub][1] = pk[((size_t)(kb0 + sub) * OUT_F + nc1) * 4 + lq];
        }
    }
    short8 cb[4][2];
    if (chblk) {
        #pragma unroll
        for (int s4 = 0; s4 < 4; ++s4) {
            cb[s4][0] = *reinterpret_cast<const short8*>(
                pkc + ((size_t)s4 * OUT_F + nc0) * 32 + lq * 8);
            cb[s4][1] = *reinterpret_cast<const short8*>(
                pkc + ((size_t)s4 * OUT_F + nc1) * 32 + lq * 8);
        }
    }
    float sc[4][2];
    #pragma unroll
    for (int gi = 0; gi < 4; ++gi) {
        if (gi * 4 < nsubn) {
            sc[gi][0] = scales[(size_t)(ky * 4 + gi) * OUT_F + nc0];
            sc[gi][1] = scales[(size_t)(ky * 4 + gi) * OUT_F + nc1];
        }
    }

    float4v acc[4][2];
    #pragma unroll
    for (int mt = 0; mt < 4; ++mt)
        #pragma unroll
        for (int nf = 0; nf < 2; ++nf) acc[mt][nf] = (float4v){0.f, 0.f, 0.f, 0.f};

    const unsigned short* xpb = xp + kbase + lq * 8;
    short8 a_cur[4], a_nxt[4];
    #pragma unroll
    for (int mt = 0; mt < 4; ++mt)
        a_cur[mt] = *reinterpret_cast<const short8*>(xpb + (size_t)(mt * 16 + ln) * IN_F);

    #pragma unroll
    for (int sub = 0; sub < 16; ++sub) {
        short8 bf0, bf1;
        if (!chblk || sub < 12) {
            const float s0 = sc[sub >> 2][0], s1 = sc[sub >> 2][1];
            union { short8 v; unsigned u[4]; } w0, w1;
            #pragma unroll
            for (int i = 0; i < 4; ++i) {
                const unsigned y0 = (bq[sub][0] >> (8 * i)) & 0xFFu;
                const unsigned y1 = (bq[sub][1] >> (8 * i)) & 0xFFu;
                w0.u[i] = pk_bf16((float)((int)(y0 & 0xFu) - 8) * s0,
                                  (float)((int)(y0 >> 4) - 8) * s0);
                w1.u[i] = pk_bf16((float)((int)(y1 & 0xFu) - 8) * s1,
                                  (float)((int)(y1 >> 4) - 8) * s1);
            }
            bf0 = w0.v; bf1 = w1.v;
        } else {
            bf0 = cb[sub - 12][0]; bf1 = cb[sub - 12][1];
        }
        if (sub < 15) {
            #pragma unroll
            for (int mt = 0; mt < 4; ++mt)
                a_nxt[mt] = *reinterpret_cast<const short8*>(
                    xpb + (size_t)(mt * 16 + ln) * IN_F + (sub + 1) * 32);
        }
        #pragma unroll
        for (int mt = 0; mt < 4; ++mt) {
            acc[mt][0] = __builtin_amdgcn_mfma_f32_16x16x32_bf16(a_cur[mt], bf0, acc[mt][0], 0, 0, 0);
            acc[mt][1] = __builtin_amdgcn_mfma_f32_16x16x32_bf16(a_cur[mt], bf1, acc[mt][1], 0, 0, 0);
        }
        if (sub < 15) {
            #pragma unroll
            for (int mt = 0; mt < 4; ++mt) a_cur[mt] = a_nxt[mt];
        }
    }

    // Epilogue: D col = ln -> n, row = lq*4 + r -> m; atomic partials
    #pragma unroll
    for (int mt = 0; mt < 4; ++mt) {
        #pragma unroll
        for (int nf = 0; nf < 2; ++nf) {
            const int n = n0w + nf * 16 + ln;
            #pragma unroll
            for (int r = 0; r < 4; ++r) {
                const int m = mt * 16 + (lq << 2) + r;
                atomicAdd(&out[(size_t)m * OUT_F + n], acc[mt][nf][r]);
            }
        }
    }
}

extern "C" void kernel_launch(void* const* d_in, const int* in_sizes, int n_in,
                              void* d_out, int out_size, void* d_ws, size_t ws_size,
                              hipStream_t stream) {
    const float* x      = (const float*)d_in[0];
    const int*   qw     = (const int*)d_in[1];     // uint8 widened to int32 by harness
    const float* cw     = (const float*)d_in[2];
    const int*   cidx   = (const int*)d_in[3];
    const float* scales = (const float*)d_in[4];
    const float* bias   = (const float*)d_in[5];
    float*       out    = (float*)d_out;

    // workspace layout (ws >= ~300 MB per harness poison traffic)
    unsigned short* xp  = (unsigned short*)d_ws;                       // 512 KB
    unsigned char*  pkn = (unsigned char*)d_ws + (512 << 10);          // 124*11008*16 B
    unsigned short* pkc = (unsigned short*)((char*)d_ws + (512 << 10)
                              + (size_t)KB_N * OUT_F * 16);            // 4*11008*64 B

    init_out<<<(BATCH * OUT_F / 4) / 256, 256, 0, stream>>>(bias, out);
    dim3 pgrid(IN_F / 256, BATCH);
    permute_x<<<pgrid, 256, 0, stream>>>(x, cidx, xp);
    repack_n<<<dim3(OUT_F / 256, KB_N), 256, 0, stream>>>(qw, pkn);
    repack_ch<<<dim3(OUT_F / 256, 4), 256, 0, stream>>>(cw, pkc);
    qgemm<<<dim3(OUT_F / 128, KSPLIT), 256, 0, stream>>>(
        xp, (const unsigned*)pkn, pkc, scales, out);
}

// Round 8
// 163.527 us; speedup vs baseline: 1.2007x; 1.2007x over previous
//
#include <hip/hip_runtime.h>
#include <hip/hip_bf16.h>
#include <stdint.h>

#define IN_F 4096
#define OUT_F 11008
#define NUM_CH 128
#define NUM_NORM 3968
#define BATCH 64
#define KSPLIT 8
#define KCHUNK (IN_F / KSPLIT)   // 512
#define NMEGA (KCHUNK / 128)     // 4 megasteps of K=128 per block
#define BS 136                   // LDS k-stride in shorts (conflict-free, 16B-aligned)

typedef short short8 __attribute__((ext_vector_type(8)));
typedef float float4v __attribute__((ext_vector_type(4)));
typedef int int4v __attribute__((ext_vector_type(4)));

__device__ __forceinline__ unsigned short f2bf(float f) {
    union { float f; unsigned u; } v; v.f = f;
    unsigned u = v.u;
    return (unsigned short)((u + 0x7FFFu + ((u >> 16) & 1u)) >> 16);
}

__device__ __forceinline__ unsigned pk_bf16(float lo, float hi) {
    __hip_bfloat162 h = __float22bfloat162_rn(make_float2(lo, hi));  // v_cvt_pk_bf16_f32
    union { __hip_bfloat162 h; unsigned u; } c; c.h = h; return c.u;
}

// Gather-permute x into bf16 xp[64][4096]:
//   pos j in [0,3968): x[:, normal_idx[j]]   pos 3968+c: x[:, cherry_indices[c]]
__global__ __launch_bounds__(256) void permute_x(
        const float* __restrict__ x, const int* __restrict__ cidx,
        unsigned short* __restrict__ xp) {
    int i = blockIdx.x * blockDim.x + threadIdx.x;
    int b = blockIdx.y;
    int lo = 0, hi = NUM_CH;
    while (lo < hi) { int mid = (lo + hi) >> 1; if (cidx[mid] < i) lo = mid + 1; else hi = mid; }
    bool isch = (lo < NUM_CH) && (cidx[lo] == i);
    int pos = isch ? (NUM_NORM + lo) : (i - lo);
    xp[b * IN_F + pos] = f2bf(x[b * IN_F + i]);
}

// out[m][n] = bias[n] + sum_ky part[ky][m][n]
__global__ __launch_bounds__(256) void reduce_out(
        const float* __restrict__ part, const float* __restrict__ bias,
        float* __restrict__ out) {
    const int i = blockIdx.x * 256 + threadIdx.x;          // float4 index
    const int c = i % (OUT_F / 4);
    float4v s = *reinterpret_cast<const float4v*>(bias + c * 4);
    #pragma unroll
    for (int ky = 0; ky < KSPLIT; ++ky) {
        const float4v p = reinterpret_cast<const float4v*>(
            part + (size_t)ky * BATCH * OUT_F)[i];
        s = (float4v){s[0] + p[0], s[1] + p[1], s[2] + p[2], s[3] + p[3]};
    }
    reinterpret_cast<float4v*>(out)[i] = s;
}

// Fused dequant + bf16 MFMA GEMM (R5 structure: K-megastep=128, dbuf LDS,
// one barrier per megastep, register prefetch a megastep ahead).
// ONLY change vs R5: epilogue stores partials (plain stores) instead of
// device-scope atomicAdd -- A/B test of the atomic-throughput hypothesis.
__global__ __launch_bounds__(256, 4) void qgemm(
        const unsigned short* __restrict__ xp, const int* __restrict__ qw,
        const float* __restrict__ cw, const float* __restrict__ scales,
        float* __restrict__ part) {
    __shared__ unsigned short Bt[2][64][BS];   // 2 x 17 KB

    const int tid  = threadIdx.x;
    const int wave = tid >> 6;
    const int lane = tid & 63;
    const int ln   = lane & 15;
    const int lq   = lane >> 4;
    const int n0    = blockIdx.x * 64;
    const int kbase = blockIdx.y * KCHUNK;
    const int tcol = (tid & 15) << 2;   // staging col offset 0..60
    const int trow = tid >> 4;          // staging row group 0..15

    const int*   qbase = qw + n0 + tcol;
    const float* sbase = scales + n0 + tcol;
    const float* cbase = cw + n0 + tcol;

    float4v acc[4];
    #pragma unroll
    for (int s = 0; s < 4; ++s) acc[s] = (float4v){0.f, 0.f, 0.f, 0.f};

    // ---- prologue: issue loads for megastep 0 (always normal region) ----
    int4v qcur[4]; float4v scur;
    {
        const int rb = (kbase >> 1) + 4 * trow;
        #pragma unroll
        for (int i = 0; i < 4; ++i)
            qcur[i] = *reinterpret_cast<const int4v*>(qbase + (size_t)(rb + i) * OUT_F);
        scur = *reinterpret_cast<const float4v*>(sbase + (size_t)(kbase >> 7) * OUT_F);
    }

    for (int s = 0; s < NMEGA; ++s) {
        const int k0 = kbase + s * 128;
        unsigned short (*buf)[BS] = Bt[s & 1];

        if (k0 < NUM_NORM) {
            const int4v q0 = qcur[0], q1 = qcur[1], q2 = qcur[2], q3 = qcur[3];
            const float4v sc = scur;
            // prefetch next megastep's raw data
            const int kn = k0 + 128;
            if (s + 1 < NMEGA && kn < NUM_NORM) {
                const int rb = (kn >> 1) + 4 * trow;
                #pragma unroll
                for (int i = 0; i < 4; ++i)
                    qcur[i] = *reinterpret_cast<const int4v*>(qbase + (size_t)(rb + i) * OUT_F);
                scur = *reinterpret_cast<const float4v*>(sbase + (size_t)(kn >> 7) * OUT_F);
            }
            const int4v qq[4] = {q0, q1, q2, q3};
            #pragma unroll
            for (int cc = 0; cc < 4; ++cc) {
                union { short8 v; unsigned u[4]; } wv;
                const float s1 = sc[cc];
                #pragma unroll
                for (int i = 0; i < 4; ++i) {
                    const int q = qq[i][cc];
                    wv.u[i] = pk_bf16((float)((q & 0xF) - 8) * s1,
                                      (float)(((q >> 4) & 0xF) - 8) * s1);
                }
                *reinterpret_cast<short8*>(&buf[tcol + cc][trow * 8]) = wv.v;
            }
        } else {
            // pure-cherry megastep (k0 == NUM_NORM; only block ky==7, s==3)
            float4v ch[8];
            #pragma unroll
            for (int j = 0; j < 8; ++j)
                ch[j] = *reinterpret_cast<const float4v*>(
                    cbase + (size_t)(8 * trow + j) * OUT_F);
            #pragma unroll
            for (int cc = 0; cc < 4; ++cc) {
                union { short8 v; unsigned u[4]; } wv;
                #pragma unroll
                for (int m = 0; m < 4; ++m)
                    wv.u[m] = pk_bf16(ch[2 * m][cc], ch[2 * m + 1][cc]);
                *reinterpret_cast<short8*>(&buf[tcol + cc][trow * 8]) = wv.v;
            }
        }

        __syncthreads();   // the ONLY barrier per megastep (dbuf covers WAR)

        const unsigned short* xprow =
            xp + (size_t)((wave << 4) + ln) * IN_F + k0 + (lq << 3);
        const short8 a0 = *reinterpret_cast<const short8*>(xprow);
        const short8 a1 = *reinterpret_cast<const short8*>(xprow + 32);
        const short8 a2 = *reinterpret_cast<const short8*>(xprow + 64);
        const short8 a3 = *reinterpret_cast<const short8*>(xprow + 96);

        #pragma unroll
        for (int st = 0; st < 4; ++st) {
            const unsigned short* bp = &buf[(st << 4) + ln][lq << 3];
            acc[st] = __builtin_amdgcn_mfma_f32_16x16x32_bf16(
                a0, *reinterpret_cast<const short8*>(bp), acc[st], 0, 0, 0);
            acc[st] = __builtin_amdgcn_mfma_f32_16x16x32_bf16(
                a1, *reinterpret_cast<const short8*>(bp + 32), acc[st], 0, 0, 0);
            acc[st] = __builtin_amdgcn_mfma_f32_16x16x32_bf16(
                a2, *reinterpret_cast<const short8*>(bp + 64), acc[st], 0, 0, 0);
            acc[st] = __builtin_amdgcn_mfma_f32_16x16x32_bf16(
                a3, *reinterpret_cast<const short8*>(bp + 96), acc[st], 0, 0, 0);
        }
    }

    // Epilogue: plain partial stores (no atomics). part[ky][m][n].
    float* pbase = part + (size_t)blockIdx.y * BATCH * OUT_F;
    #pragma unroll
    for (int st = 0; st < 4; ++st) {
        const int n = n0 + (st << 4) + ln;
        #pragma unroll
        for (int r = 0; r < 4; ++r) {
            const int m = (wave << 4) + (lq << 2) + r;
            pbase[(size_t)m * OUT_F + n] = acc[st][r];
        }
    }
}

extern "C" void kernel_launch(void* const* d_in, const int* in_sizes, int n_in,
                              void* d_out, int out_size, void* d_ws, size_t ws_size,
                              hipStream_t stream) {
    const float* x      = (const float*)d_in[0];
    const int*   qw     = (const int*)d_in[1];     // uint8 widened to int32 by harness
    const float* cw     = (const float*)d_in[2];
    const int*   cidx   = (const int*)d_in[3];
    const float* scales = (const float*)d_in[4];
    const float* bias   = (const float*)d_in[5];
    float*       out    = (float*)d_out;

    unsigned short* xp   = (unsigned short*)d_ws;                    // 512 KB
    float*          part = (float*)((char*)d_ws + (512 << 10));      // 8*64*11008*4 = 22.5 MB

    dim3 pgrid(IN_F / 256, BATCH);
    permute_x<<<pgrid, 256, 0, stream>>>(x, cidx, xp);
    qgemm<<<dim3(OUT_F / 64, KSPLIT), 256, 0, stream>>>(xp, qw, cw, scales, part);
    reduce_out<<<(BATCH * OUT_F / 4) / 256, 256, 0, stream>>>(part, bias, out);
}

// Round 9
// 161.084 us; speedup vs baseline: 1.2189x; 1.0152x over previous
//
#include <hip/hip_runtime.h>
#include <hip/hip_bf16.h>
#include <stdint.h>

#define IN_F 4096
#define OUT_F 11008
#define NUM_CH 128
#define NUM_NORM 3968
#define BATCH 64
#define KSPLIT 8
#define KCHUNK (IN_F / KSPLIT)   // 512
#define NMEGA (KCHUNK / 128)     // 4 megasteps of K=128 per block
#define BS 136                   // LDS k-stride in shorts (16B-aligned)

typedef short short8 __attribute__((ext_vector_type(8)));
typedef float float4v __attribute__((ext_vector_type(4)));
typedef int int4v __attribute__((ext_vector_type(4)));

// Barrier WITHOUT the implicit s_waitcnt vmcnt(0) drain of __syncthreads().
// Waits only for this wave's own LDS ops (lgkmcnt); cross-wave LDS visibility
// is provided by the in-order DS pipe + the barrier. Global prefetch loads
// issued before this stay in flight across it (the whole point).
__device__ __forceinline__ void barrier_no_vmcnt() {
    asm volatile("s_waitcnt lgkmcnt(0)\n\ts_barrier" ::: "memory");
}

__device__ __forceinline__ unsigned short f2bf(float f) {
    union { float f; unsigned u; } v; v.f = f;
    unsigned u = v.u;
    return (unsigned short)((u + 0x7FFFu + ((u >> 16) & 1u)) >> 16);
}

__device__ __forceinline__ unsigned pk_bf16(float lo, float hi) {
    __hip_bfloat162 h = __float22bfloat162_rn(make_float2(lo, hi));  // v_cvt_pk_bf16_f32
    union { __hip_bfloat162 h; unsigned u; } c; c.h = h; return c.u;
}

// Gather-permute x into bf16 xp[64][4096]
__global__ __launch_bounds__(256) void permute_x(
        const float* __restrict__ x, const int* __restrict__ cidx,
        unsigned short* __restrict__ xp) {
    int i = blockIdx.x * blockDim.x + threadIdx.x;
    int b = blockIdx.y;
    int lo = 0, hi = NUM_CH;
    while (lo < hi) { int mid = (lo + hi) >> 1; if (cidx[mid] < i) lo = mid + 1; else hi = mid; }
    bool isch = (lo < NUM_CH) && (cidx[lo] == i);
    int pos = isch ? (NUM_NORM + lo) : (i - lo);
    xp[b * IN_F + pos] = f2bf(x[b * IN_F + i]);
}

// out[m][n] = bias[n] + sum_ky part[ky][m][n]
__global__ __launch_bounds__(256) void reduce_out(
        const float* __restrict__ part, const float* __restrict__ bias,
        float* __restrict__ out) {
    const int i = blockIdx.x * 256 + threadIdx.x;          // float4 index
    const int c = i % (OUT_F / 4);
    float4v s = *reinterpret_cast<const float4v*>(bias + c * 4);
    #pragma unroll
    for (int ky = 0; ky < KSPLIT; ++ky) {
        const float4v p = reinterpret_cast<const float4v*>(
            part + (size_t)ky * BATCH * OUT_F)[i];
        s = (float4v){s[0] + p[0], s[1] + p[1], s[2] + p[2], s[3] + p[3]};
    }
    reinterpret_cast<float4v*>(out)[i] = s;
}

// Fused dequant + bf16 MFMA GEMM. R8 structure; ONLY change: the megastep
// barrier no longer drains vmcnt, so the megastep-ahead global prefetch
// finally stays in flight across the barrier (A/B test of the drain theory).
__global__ __launch_bounds__(256, 4) void qgemm(
        const unsigned short* __restrict__ xp, const int* __restrict__ qw,
        const float* __restrict__ cw, const float* __restrict__ scales,
        float* __restrict__ part) {
    __shared__ unsigned short Bt[2][64][BS];   // 2 x 17 KB

    const int tid  = threadIdx.x;
    const int wave = tid >> 6;
    const int lane = tid & 63;
    const int ln   = lane & 15;
    const int lq   = lane >> 4;
    const int n0    = blockIdx.x * 64;
    const int kbase = blockIdx.y * KCHUNK;
    const int tcol = (tid & 15) << 2;   // staging col offset 0..60
    const int trow = tid >> 4;          // staging row group 0..15

    const int*   qbase = qw + n0 + tcol;
    const float* sbase = scales + n0 + tcol;
    const float* cbase = cw + n0 + tcol;

    float4v acc[4];
    #pragma unroll
    for (int s = 0; s < 4; ++s) acc[s] = (float4v){0.f, 0.f, 0.f, 0.f};

    // ---- prologue: issue loads for megastep 0 (always normal region) ----
    int4v qcur[4]; float4v scur;
    {
        const int rb = (kbase >> 1) + 4 * trow;
        #pragma unroll
        for (int i = 0; i < 4; ++i)
            qcur[i] = *reinterpret_cast<const int4v*>(qbase + (size_t)(rb + i) * OUT_F);
        scur = *reinterpret_cast<const float4v*>(sbase + (size_t)(kbase >> 7) * OUT_F);
    }

    for (int s = 0; s < NMEGA; ++s) {
        const int k0 = kbase + s * 128;
        unsigned short (*buf)[BS] = Bt[s & 1];

        if (k0 < NUM_NORM) {
            const int4v q0 = qcur[0], q1 = qcur[1], q2 = qcur[2], q3 = qcur[3];
            const float4v sc = scur;
            // prefetch next megastep's raw data — now genuinely stays in
            // flight until next staging phase (no vmcnt drain at barrier)
            const int kn = k0 + 128;
            if (s + 1 < NMEGA && kn < NUM_NORM) {
                const int rb = (kn >> 1) + 4 * trow;
                #pragma unroll
                for (int i = 0; i < 4; ++i)
                    qcur[i] = *reinterpret_cast<const int4v*>(qbase + (size_t)(rb + i) * OUT_F);
                scur = *reinterpret_cast<const float4v*>(sbase + (size_t)(kn >> 7) * OUT_F);
            }
            const int4v qq[4] = {q0, q1, q2, q3};
            #pragma unroll
            for (int cc = 0; cc < 4; ++cc) {
                union { short8 v; unsigned u[4]; } wv;
                const float s1 = sc[cc];
                #pragma unroll
                for (int i = 0; i < 4; ++i) {
                    const int q = qq[i][cc];
                    wv.u[i] = pk_bf16((float)((q & 0xF) - 8) * s1,
                                      (float)(((q >> 4) & 0xF) - 8) * s1);
                }
                *reinterpret_cast<short8*>(&buf[tcol + cc][trow * 8]) = wv.v;
            }
        } else {
            // pure-cherry megastep (k0 == NUM_NORM; only block ky==7, s==3)
            float4v ch[8];
            #pragma unroll
            for (int j = 0; j < 8; ++j)
                ch[j] = *reinterpret_cast<const float4v*>(
                    cbase + (size_t)(8 * trow + j) * OUT_F);
            #pragma unroll
            for (int cc = 0; cc < 4; ++cc) {
                union { short8 v; unsigned u[4]; } wv;
                #pragma unroll
                for (int m = 0; m < 4; ++m)
                    wv.u[m] = pk_bf16(ch[2 * m][cc], ch[2 * m + 1][cc]);
                *reinterpret_cast<short8*>(&buf[tcol + cc][trow * 8]) = wv.v;
            }
        }

        barrier_no_vmcnt();   // orders LDS writes vs reads; leaves vmem in flight

        const unsigned short* xprow =
            xp + (size_t)((wave << 4) + ln) * IN_F + k0 + (lq << 3);
        const short8 a0 = *reinterpret_cast<const short8*>(xprow);
        const short8 a1 = *reinterpret_cast<const short8*>(xprow + 32);
        const short8 a2 = *reinterpret_cast<const short8*>(xprow + 64);
        const short8 a3 = *reinterpret_cast<const short8*>(xprow + 96);

        #pragma unroll
        for (int st = 0; st < 4; ++st) {
            const unsigned short* bp = &buf[(st << 4) + ln][lq << 3];
            acc[st] = __builtin_amdgcn_mfma_f32_16x16x32_bf16(
                a0, *reinterpret_cast<const short8*>(bp), acc[st], 0, 0, 0);
            acc[st] = __builtin_amdgcn_mfma_f32_16x16x32_bf16(
                a1, *reinterpret_cast<const short8*>(bp + 32), acc[st], 0, 0, 0);
            acc[st] = __builtin_amdgcn_mfma_f32_16x16x32_bf16(
                a2, *reinterpret_cast<const short8*>(bp + 64), acc[st], 0, 0, 0);
            acc[st] = __builtin_amdgcn_mfma_f32_16x16x32_bf16(
                a3, *reinterpret_cast<const short8*>(bp + 96), acc[st], 0, 0, 0);
        }
    }

    // Epilogue: plain partial stores. part[ky][m][n].
    float* pbase = part + (size_t)blockIdx.y * BATCH * OUT_F;
    #pragma unroll
    for (int st = 0; st < 4; ++st) {
        const int n = n0 + (st << 4) + ln;
        #pragma unroll
        for (int r = 0; r < 4; ++r) {
            const int m = (wave << 4) + (lq << 2) + r;
            pbase[(size_t)m * OUT_F + n] = acc[st][r];
        }
    }
}

extern "C" void kernel_launch(void* const* d_in, const int* in_sizes, int n_in,
                              void* d_out, int out_size, void* d_ws, size_t ws_size,
                              hipStream_t stream) {
    const float* x      = (const float*)d_in[0];
    const int*   qw     = (const int*)d_in[1];     // uint8 widened to int32 by harness
    const float* cw     = (const float*)d_in[2];
    const int*   cidx   = (const int*)d_in[3];
    const float* scales = (const float*)d_in[4];
    const float* bias   = (const float*)d_in[5];
    float*       out    = (float*)d_out;

    unsigned short* xp   = (unsigned short*)d_ws;                    // 512 KB
    float*          part = (float*)((char*)d_ws + (512 << 10));      // 22.5 MB

    dim3 pgrid(IN_F / 256, BATCH);
    permute_x<<<pgrid, 256, 0, stream>>>(x, cidx, xp);
    qgemm<<<dim3(OUT_F / 64, KSPLIT), 256, 0, stream>>>(xp, qw, cw, scales, part);
    reduce_out<<<(BATCH * OUT_F / 4) / 256, 256, 0, stream>>>(part, bias, out);
}